// Round 15
// baseline (41.116 us; speedup 1.0000x reference)
//
#include <hip/hip_runtime.h>

// B=64, H=W=512, K=7, VALID conv -> 506x506.
// v14 = v12 (guard-free shifted tiling, aligned float4 loads, SGPR weights)
//       + 5-deep software pipeline enforced with sched_barrier(0).
// v13 post-mortem: without fences the scheduler sank the pipelined loads
// back to just-before-use (identical 36-VGPR binary as v12, MLP=3,
// per-wave duty ~6%). sched_barrier(0) forbids instruction motion across
// the fence in BOTH directions, so each region keeps exactly
// {issue row ir+5} | {compute row ir}: 12-15 loads in flight per wave,
// ~4 rows of FMA (~1500cyc) between issue and use >> 900cyc HBM latency.
// No __launch_bounds__ cap (v3/v4/v7 spill disasters). Plain stores.
#define HW 512
#define OW 506

__device__ __forceinline__ float elem3(const float4 (&b)[3], int e) {
    // e compile-time after unroll -> folds to a direct register reference
    const float4& q = b[e >> 2];
    switch (e & 3) {
        case 0:  return q.x;
        case 1:  return q.y;
        case 2:  return q.z;
        default: return q.w;
    }
}

template<int SH>
__device__ __forceinline__ void conv_pipe(const float* __restrict__ p0,
                                          const float (&wv)[49],
                                          float (&acc)[16]) {
    float4 buf[5][3];   // 5-row rotating buffer, statically indexed

    // ---- prologue: issue rows 0..4 (15 float4 loads in flight) ----
#pragma unroll
    for (int r = 0; r < 5; ++r) {
        const float* p = p0 + r * HW;
        buf[r][0] = *reinterpret_cast<const float4*>(p);
        buf[r][1] = *reinterpret_cast<const float4*>(p + 4);
        buf[r][2] = *reinterpret_cast<const float4*>(p + 8);
    }
    __builtin_amdgcn_sched_barrier(0);

    // ---- steady state: compute row ir | issue row ir+5, fenced ----
#pragma unroll
    for (int ir = 0; ir < 10; ++ir) {
        const int slot = ir % 5;                 // static after unroll

#pragma unroll
        for (int kr = 0; kr < 7; ++kr) {
            const int s = ir - kr;               // static after unroll
            if (s >= 0 && s < 4) {
#pragma unroll
                for (int kc = 0; kc < 7; ++kc) {
                    const float wk = wv[kr * 7 + kc];
#pragma unroll
                    for (int j = 0; j < 4; ++j)
                        acc[s * 4 + j] = fmaf(wk, elem3(buf[slot], SH + kc + j),
                                              acc[s * 4 + j]);
                }
            }
        }
        __builtin_amdgcn_sched_barrier(0);       // compute stays in its region

        if (ir + 5 < 10) {                       // refill freed slot
            const float* p = p0 + (ir + 5) * HW;
            buf[slot][0] = *reinterpret_cast<const float4*>(p);
            buf[slot][1] = *reinterpret_cast<const float4*>(p + 4);
            buf[slot][2] = *reinterpret_cast<const float4*>(p + 8);
            __builtin_amdgcn_sched_barrier(0);   // loads can't sink or hoist
        }
    }
}

__global__ __launch_bounds__(256) void conv7x7_v14(
    const float* __restrict__ in,      // [64][512][512]
    const float* __restrict__ weight,  // [7][7]
    const float* __restrict__ bias,    // [1]
    float* __restrict__ out)           // [64][506][506]
{
    const int tid  = threadIdx.x;
    const int lane = tid & 63;
    const int w    = tid >> 6;
    const int bx   = blockIdx.x;                // 0 or 1
    const int x0   = bx ? 250 : 0;              // tiles cover 0..255, 250..505
    const int y0   = min((int)blockIdx.y * 16, OW - 16);  // shifted last tile
    const int yb   = y0 + w * 4;                // wave's first output row (<=502)
    const int b    = blockIdx.z;

    // ---- weights + bias -> SGPRs (uniform, statically indexed) ----
    float wv[49];
#pragma unroll
    for (int i = 0; i < 49; ++i)
        wv[i] = __uint_as_float(__builtin_amdgcn_readfirstlane(__float_as_uint(weight[i])));
    const float bv = __uint_as_float(__builtin_amdgcn_readfirstlane(__float_as_uint(bias[0])));

    const float* __restrict__ ib = in + (size_t)b * (HW * HW);

    const int cb = x0 + 4 * lane;               // first output col
    // Aligned load base: bx=0 -> cb (==0 mod 4), window [cb..cb+11] <= 263.
    //                    bx=1 -> cb-2 (==0 mod 4), window [cb-2..cb+9] <= 511.
    const float* p0 = ib + (size_t)yb * HW + (cb - (bx ? 2 : 0));

    float acc[16];
#pragma unroll
    for (int i = 0; i < 16; ++i) acc[i] = 0.f;

    if (bx == 0) conv_pipe<0>(p0, wv, acc);     // uniform SGPR branch
    else         conv_pipe<2>(p0, wv, acc);

    // ---- store: 4 rows x 4 cols, two float2 per row, unguarded ----
    float* __restrict__ outb = out + (size_t)b * (OW * OW);
#pragma unroll
    for (int s = 0; s < 4; ++s) {
        float* orow = outb + (size_t)(yb + s) * OW + cb;   // cb even -> 8B aligned
        *reinterpret_cast<float2*>(orow) =
            make_float2(acc[s * 4 + 0] + bv, acc[s * 4 + 1] + bv);
        *reinterpret_cast<float2*>(orow + 2) =
            make_float2(acc[s * 4 + 2] + bv, acc[s * 4 + 3] + bv);
    }
}

extern "C" void kernel_launch(void* const* d_in, const int* in_sizes, int n_in,
                              void* d_out, int out_size, void* d_ws, size_t ws_size,
                              hipStream_t stream) {
    const float* enc_x  = (const float*)d_in[0];
    const float* weight = (const float*)d_in[1];
    const float* bias   = (const float*)d_in[2];
    float* outp         = (float*)d_out;

    // x: 2 overlapping 256-col tiles; y: 32 tiles of 16 rows (last shifted);
    // z: 64 images. 4096 blocks.
    dim3 grid(2, 32, 64);
    dim3 block(256);
    hipLaunchKernelGGL(conv7x7_v14, grid, block, 0, stream,
                       enc_x, weight, bias, outp);
}

// Round 17
// 33.935 us; speedup vs baseline: 1.2116x; 1.2116x over previous
//
#include <hip/hip_runtime.h>

// B=64, H=W=512, K=7, VALID conv -> 506x506.
// v16 = v15 with the load-asm early-clobber fix.
// v15 post-mortem: "=v" (no early-clobber) let the allocator overlap a load
// DEST tuple with the address pair %3; the first async load clobbered the
// address before loads 2/3 issued -> wild address -> GPU fault. "=&v" forces
// disjoint registers. Pipeline logic unchanged: 12 loads in flight,
// counted vmcnt(9) per row, tied "+v" waits pin FMAs after the waitcnt.
#define HW 512
#define OW 506

typedef float vf4 __attribute__((ext_vector_type(4)));

// 3 x global_load_dwordx4 from a 64-bit VGPR address + 13-bit immediates.
// "=&v": early-clobber -- dest tuples must not overlap the address pair.
#define LOAD_ROW(d0, d1, d2, addr, O0, O1, O2)                        \
    asm volatile("global_load_dwordx4 %0, %3, off offset:" #O0 "\n\t" \
                 "global_load_dwordx4 %1, %3, off offset:" #O1 "\n\t" \
                 "global_load_dwordx4 %2, %3, off offset:" #O2        \
                 : "=&v"(d0), "=&v"(d1), "=&v"(d2)                    \
                 : "v"(addr) : "memory")

// Counted wait; "+v" redefines the row's registers so consumers must
// follow the wait (SSA data dependence beats any scheduler).
#define WAIT_ROW(d0, d1, d2, N)                                       \
    asm volatile("s_waitcnt vmcnt(" #N ")"                            \
                 : "+v"(d0), "+v"(d1), "+v"(d2))

template<int SH>
__device__ __forceinline__ void row_fma(int ir, const vf4 (&b)[3],
                                        const float (&wv)[49],
                                        float (&acc)[16]) {
#pragma unroll
    for (int kr = 0; kr < 7; ++kr) {
        const int s = ir - kr;               // constant after caller unroll
        if (s >= 0 && s < 4) {
#pragma unroll
            for (int kc = 0; kc < 7; ++kc) {
                const float wk = wv[kr * 7 + kc];
#pragma unroll
                for (int j = 0; j < 4; ++j) {
                    const int e = SH + kc + j;          // 0..11, constant
                    acc[s * 4 + j] = fmaf(wk, b[e >> 2][e & 3], acc[s * 4 + j]);
                }
            }
        }
    }
}

template<int SH>
__device__ __forceinline__ void conv_pipe(const float* __restrict__ p0,
                                          const float (&wv)[49],
                                          float (&acc)[16]) {
    vf4 buf[4][3];                            // 4-row rotating buffer (48 VGPR)
    // one 64-bit address per row-pair; row 2k+1 via offset 2048 (=HW*4B)
    const float* a0 = p0;
    const float* a1 = p0 + 2 * HW;
    const float* a2 = p0 + 4 * HW;
    const float* a3 = p0 + 6 * HW;
    const float* a4 = p0 + 8 * HW;

    // prologue: rows 0..3 -> 12 loads in flight
    LOAD_ROW(buf[0][0], buf[0][1], buf[0][2], a0, 0, 16, 32);
    LOAD_ROW(buf[1][0], buf[1][1], buf[1][2], a0, 2048, 2064, 2080);
    LOAD_ROW(buf[2][0], buf[2][1], buf[2][2], a1, 0, 16, 32);
    LOAD_ROW(buf[3][0], buf[3][1], buf[3][2], a1, 2048, 2064, 2080);

    // steady state: wait row k (counted) -> 196 FMA -> issue row k+4
    WAIT_ROW(buf[0][0], buf[0][1], buf[0][2], 9);
    row_fma<SH>(0, buf[0], wv, acc);
    LOAD_ROW(buf[0][0], buf[0][1], buf[0][2], a2, 0, 16, 32);        // row 4

    WAIT_ROW(buf[1][0], buf[1][1], buf[1][2], 9);
    row_fma<SH>(1, buf[1], wv, acc);
    LOAD_ROW(buf[1][0], buf[1][1], buf[1][2], a2, 2048, 2064, 2080); // row 5

    WAIT_ROW(buf[2][0], buf[2][1], buf[2][2], 9);
    row_fma<SH>(2, buf[2], wv, acc);
    LOAD_ROW(buf[2][0], buf[2][1], buf[2][2], a3, 0, 16, 32);        // row 6

    WAIT_ROW(buf[3][0], buf[3][1], buf[3][2], 9);
    row_fma<SH>(3, buf[3], wv, acc);
    LOAD_ROW(buf[3][0], buf[3][1], buf[3][2], a3, 2048, 2064, 2080); // row 7

    WAIT_ROW(buf[0][0], buf[0][1], buf[0][2], 9);
    row_fma<SH>(4, buf[0], wv, acc);
    LOAD_ROW(buf[0][0], buf[0][1], buf[0][2], a4, 0, 16, 32);        // row 8

    WAIT_ROW(buf[1][0], buf[1][1], buf[1][2], 9);
    row_fma<SH>(5, buf[1], wv, acc);
    LOAD_ROW(buf[1][0], buf[1][1], buf[1][2], a4, 2048, 2064, 2080); // row 9

    WAIT_ROW(buf[2][0], buf[2][1], buf[2][2], 9);
    row_fma<SH>(6, buf[2], wv, acc);
    WAIT_ROW(buf[3][0], buf[3][1], buf[3][2], 6);
    row_fma<SH>(7, buf[3], wv, acc);
    WAIT_ROW(buf[0][0], buf[0][1], buf[0][2], 3);
    row_fma<SH>(8, buf[0], wv, acc);
    WAIT_ROW(buf[1][0], buf[1][1], buf[1][2], 0);
    row_fma<SH>(9, buf[1], wv, acc);
}

__global__ __launch_bounds__(256) void conv7x7_v16(
    const float* __restrict__ in,      // [64][512][512]
    const float* __restrict__ weight,  // [7][7]
    const float* __restrict__ bias,    // [1]
    float* __restrict__ out)           // [64][506][506]
{
    const int tid  = threadIdx.x;
    const int lane = tid & 63;
    const int w    = tid >> 6;
    const int bx   = blockIdx.x;                // 0 or 1
    const int x0   = bx ? 250 : 0;              // tiles cover 0..255, 250..505
    const int y0   = min((int)blockIdx.y * 16, OW - 16);  // shifted last tile
    const int yb   = y0 + w * 4;                // wave's first output row (<=502)
    const int b    = blockIdx.z;

    // ---- weights + bias -> SGPRs (uniform, statically indexed) ----
    float wv[49];
#pragma unroll
    for (int i = 0; i < 49; ++i)
        wv[i] = __uint_as_float(__builtin_amdgcn_readfirstlane(__float_as_uint(weight[i])));
    const float bv = __uint_as_float(__builtin_amdgcn_readfirstlane(__float_as_uint(bias[0])));

    const float* __restrict__ ib = in + (size_t)b * (HW * HW);

    const int cb = x0 + 4 * lane;               // first output col
    // Aligned base: bx=0 -> cb (==0 mod 4), window [cb..cb+11] <= 263.
    //               bx=1 -> cb-2 (==0 mod 4), window [cb-2..cb+9] <= 511.
    const float* p0 = ib + (size_t)yb * HW + (cb - (bx ? 2 : 0));

    float acc[16];
#pragma unroll
    for (int i = 0; i < 16; ++i) acc[i] = 0.f;

    if (bx == 0) conv_pipe<0>(p0, wv, acc);     // uniform SGPR branch
    else         conv_pipe<2>(p0, wv, acc);

    // ---- store: 4 rows x 4 cols, two float2 per row, unguarded ----
    float* __restrict__ outb = out + (size_t)b * (OW * OW);
#pragma unroll
    for (int s = 0; s < 4; ++s) {
        float* orow = outb + (size_t)(yb + s) * OW + cb;   // cb even -> 8B aligned
        *reinterpret_cast<float2*>(orow) =
            make_float2(acc[s * 4 + 0] + bv, acc[s * 4 + 1] + bv);
        *reinterpret_cast<float2*>(orow + 2) =
            make_float2(acc[s * 4 + 2] + bv, acc[s * 4 + 3] + bv);
    }
}

extern "C" void kernel_launch(void* const* d_in, const int* in_sizes, int n_in,
                              void* d_out, int out_size, void* d_ws, size_t ws_size,
                              hipStream_t stream) {
    const float* enc_x  = (const float*)d_in[0];
    const float* weight = (const float*)d_in[1];
    const float* bias   = (const float*)d_in[2];
    float* outp         = (float*)d_out;

    // x: 2 overlapping 256-col tiles; y: 32 tiles of 16 rows (last shifted);
    // z: 64 images. 4096 blocks.
    dim3 grid(2, 32, 64);
    dim3 block(256);
    hipLaunchKernelGGL(conv7x7_v16, grid, block, 0, stream,
                       enc_x, weight, bias, outp);
}

// Round 18
// 33.233 us; speedup vs baseline: 1.2372x; 1.0211x over previous
//
#include <hip/hip_runtime.h>

// B=64, H=W=512, K=7, VALID conv -> 506x506.
// v17 = v16's asm-pinned counted-vmcnt pipeline, micro-tile deepened to
// 4 cols x 8 rows (32 outputs/thread, 14 input rows).
// v16 (33.9us) proved per-wave MLP was the lever. v17 scales efficiency:
// loads/output 1.875 -> 1.31, halo refetch down (FETCH ~51->48MB),
// 4-row pipeline fill amortized over 14 rows not 10. ~110 VGPR -> 4
// waves/SIMD, but latency hiding is now ILP (12 loads pinned in flight
// per wave), not TLP -- the v9 failure mode (4 waves, MLP=3) inverted.
#define HW 512
#define OW 506

typedef float vf4 __attribute__((ext_vector_type(4)));

// 3 x global_load_dwordx4; "=&v" early-clobber (v15 fault fix).
#define LOAD_ROW(d0, d1, d2, addr, O0, O1, O2)                        \
    asm volatile("global_load_dwordx4 %0, %3, off offset:" #O0 "\n\t" \
                 "global_load_dwordx4 %1, %3, off offset:" #O1 "\n\t" \
                 "global_load_dwordx4 %2, %3, off offset:" #O2        \
                 : "=&v"(d0), "=&v"(d1), "=&v"(d2)                    \
                 : "v"(addr) : "memory")

// Counted wait; tied "+v" operands pin consumer FMAs after the waitcnt.
#define WAIT_ROW(d0, d1, d2, N)                                       \
    asm volatile("s_waitcnt vmcnt(" #N ")"                            \
                 : "+v"(d0), "+v"(d1), "+v"(d2))

template<int SH>
__device__ __forceinline__ void row_fma(int ir, const vf4 (&b)[3],
                                        const float (&wv)[49],
                                        float (&acc)[32]) {
#pragma unroll
    for (int kr = 0; kr < 7; ++kr) {
        const int s = ir - kr;               // constant after caller unroll
        if (s >= 0 && s < 8) {
#pragma unroll
            for (int kc = 0; kc < 7; ++kc) {
                const float wk = wv[kr * 7 + kc];
#pragma unroll
                for (int j = 0; j < 4; ++j) {
                    const int e = SH + kc + j;          // 0..11, constant
                    acc[s * 4 + j] = fmaf(wk, b[e >> 2][e & 3], acc[s * 4 + j]);
                }
            }
        }
    }
}

template<int SH>
__device__ __forceinline__ void conv_pipe(const float* __restrict__ p0,
                                          const float (&wv)[49],
                                          float (&acc)[32]) {
    vf4 buf[4][3];                            // 4-row rotating buffer (48 VGPR)
    // one 64-bit address per row-pair; odd rows via offset 2048 (=HW*4B)
    const float* a0 = p0;
    const float* a1 = p0 + 2 * HW;
    const float* a2 = p0 + 4 * HW;
    const float* a3 = p0 + 6 * HW;
    const float* a4 = p0 + 8 * HW;
    const float* a5 = p0 + 10 * HW;
    const float* a6 = p0 + 12 * HW;

    // prologue: rows 0..3 -> 12 loads in flight
    LOAD_ROW(buf[0][0], buf[0][1], buf[0][2], a0, 0, 16, 32);
    LOAD_ROW(buf[1][0], buf[1][1], buf[1][2], a0, 2048, 2064, 2080);
    LOAD_ROW(buf[2][0], buf[2][1], buf[2][2], a1, 0, 16, 32);
    LOAD_ROW(buf[3][0], buf[3][1], buf[3][2], a1, 2048, 2064, 2080);

    // steady state: wait row ir (counted, 9 = keep 3 rows in flight),
    // 196 FMA, issue row ir+4 into the freed slot.
    WAIT_ROW(buf[0][0], buf[0][1], buf[0][2], 9);
    row_fma<SH>(0, buf[0], wv, acc);
    LOAD_ROW(buf[0][0], buf[0][1], buf[0][2], a2, 0, 16, 32);        // row 4

    WAIT_ROW(buf[1][0], buf[1][1], buf[1][2], 9);
    row_fma<SH>(1, buf[1], wv, acc);
    LOAD_ROW(buf[1][0], buf[1][1], buf[1][2], a2, 2048, 2064, 2080); // row 5

    WAIT_ROW(buf[2][0], buf[2][1], buf[2][2], 9);
    row_fma<SH>(2, buf[2], wv, acc);
    LOAD_ROW(buf[2][0], buf[2][1], buf[2][2], a3, 0, 16, 32);        // row 6

    WAIT_ROW(buf[3][0], buf[3][1], buf[3][2], 9);
    row_fma<SH>(3, buf[3], wv, acc);
    LOAD_ROW(buf[3][0], buf[3][1], buf[3][2], a3, 2048, 2064, 2080); // row 7

    WAIT_ROW(buf[0][0], buf[0][1], buf[0][2], 9);
    row_fma<SH>(4, buf[0], wv, acc);
    LOAD_ROW(buf[0][0], buf[0][1], buf[0][2], a4, 0, 16, 32);        // row 8

    WAIT_ROW(buf[1][0], buf[1][1], buf[1][2], 9);
    row_fma<SH>(5, buf[1], wv, acc);
    LOAD_ROW(buf[1][0], buf[1][1], buf[1][2], a4, 2048, 2064, 2080); // row 9

    WAIT_ROW(buf[2][0], buf[2][1], buf[2][2], 9);
    row_fma<SH>(6, buf[2], wv, acc);
    LOAD_ROW(buf[2][0], buf[2][1], buf[2][2], a5, 0, 16, 32);        // row 10

    WAIT_ROW(buf[3][0], buf[3][1], buf[3][2], 9);
    row_fma<SH>(7, buf[3], wv, acc);
    LOAD_ROW(buf[3][0], buf[3][1], buf[3][2], a5, 2048, 2064, 2080); // row 11

    WAIT_ROW(buf[0][0], buf[0][1], buf[0][2], 9);
    row_fma<SH>(8, buf[0], wv, acc);
    LOAD_ROW(buf[0][0], buf[0][1], buf[0][2], a6, 0, 16, 32);        // row 12

    WAIT_ROW(buf[1][0], buf[1][1], buf[1][2], 9);
    row_fma<SH>(9, buf[1], wv, acc);
    LOAD_ROW(buf[1][0], buf[1][1], buf[1][2], a6, 2048, 2064, 2080); // row 13

    // epilogue: drain 9 -> 6 -> 3 -> 0
    WAIT_ROW(buf[2][0], buf[2][1], buf[2][2], 9);
    row_fma<SH>(10, buf[2], wv, acc);
    WAIT_ROW(buf[3][0], buf[3][1], buf[3][2], 6);
    row_fma<SH>(11, buf[3], wv, acc);
    WAIT_ROW(buf[0][0], buf[0][1], buf[0][2], 3);
    row_fma<SH>(12, buf[0], wv, acc);
    WAIT_ROW(buf[1][0], buf[1][1], buf[1][2], 0);
    row_fma<SH>(13, buf[1], wv, acc);
}

__global__ __launch_bounds__(256) void conv7x7_v17(
    const float* __restrict__ in,      // [64][512][512]
    const float* __restrict__ weight,  // [7][7]
    const float* __restrict__ bias,    // [1]
    float* __restrict__ out)           // [64][506][506]
{
    const int tid  = threadIdx.x;
    const int lane = tid & 63;
    const int w    = tid >> 6;
    const int bx   = blockIdx.x;                // 0 or 1
    const int x0   = bx ? 250 : 0;              // tiles cover 0..255, 250..505
    const int y0   = min((int)blockIdx.y * 32, OW - 32);  // shifted last tile
    const int yb   = y0 + w * 8;                // wave's first output row (<=498)
    const int b    = blockIdx.z;

    // ---- weights + bias -> SGPRs (uniform, statically indexed) ----
    float wv[49];
#pragma unroll
    for (int i = 0; i < 49; ++i)
        wv[i] = __uint_as_float(__builtin_amdgcn_readfirstlane(__float_as_uint(weight[i])));
    const float bv = __uint_as_float(__builtin_amdgcn_readfirstlane(__float_as_uint(bias[0])));

    const float* __restrict__ ib = in + (size_t)b * (HW * HW);

    const int cb = x0 + 4 * lane;               // first output col (<=502)
    // Aligned base: bx=0 -> cb (==0 mod 4), window [cb..cb+11] <= 263.
    //               bx=1 -> cb-2 (==0 mod 4), window [cb-2..cb+9] <= 511.
    // Rows yb..yb+13 <= 511 by shifted y-tiling.
    const float* p0 = ib + (size_t)yb * HW + (cb - (bx ? 2 : 0));

    float acc[32];
#pragma unroll
    for (int i = 0; i < 32; ++i) acc[i] = 0.f;

    if (bx == 0) conv_pipe<0>(p0, wv, acc);     // uniform SGPR branch
    else         conv_pipe<2>(p0, wv, acc);

    // ---- store: 8 rows x 4 cols, two float2 per row, unguarded ----
    float* __restrict__ outb = out + (size_t)b * (OW * OW);
#pragma unroll
    for (int s = 0; s < 8; ++s) {
        float* orow = outb + (size_t)(yb + s) * OW + cb;   // cb even -> 8B aligned
        *reinterpret_cast<float2*>(orow) =
            make_float2(acc[s * 4 + 0] + bv, acc[s * 4 + 1] + bv);
        *reinterpret_cast<float2*>(orow + 2) =
            make_float2(acc[s * 4 + 2] + bv, acc[s * 4 + 3] + bv);
    }
}

extern "C" void kernel_launch(void* const* d_in, const int* in_sizes, int n_in,
                              void* d_out, int out_size, void* d_ws, size_t ws_size,
                              hipStream_t stream) {
    const float* enc_x  = (const float*)d_in[0];
    const float* weight = (const float*)d_in[1];
    const float* bias   = (const float*)d_in[2];
    float* outp         = (float*)d_out;

    // x: 2 overlapping 256-col tiles; y: 16 tiles of 32 rows (last shifted);
    // z: 64 images. 2048 blocks = 8/CU.
    dim3 grid(2, 16, 64);
    dim3 block(256);
    hipLaunchKernelGGL(conv7x7_v17, grid, block, 0, stream,
                       enc_x, weight, bias, outp);
}